// Round 9
// baseline (155.139 us; speedup 1.0000x reference)
//
#include <hip/hip_runtime.h>

// EndEffectorLoss: rot6d -> R, FK over fixed 24-joint tree, end-effector MSE.
// R9 = R6's 5-chain thread decomposition (5x waves, 52-VGPR spill-free chains)
// + R7's coalesced LDS staging (kills per-lane 576B-stride request blowup).
// Block = 640 threads = 10 waves = 5 chains x {A,B} on 64 frames. All threads
// cooperatively stage BOTH full pose arrays into LDS (float4-coalesced, row
// pad 146: gcd(146,32)=2 -> 2-way = free, even rows -> b64 FK reads), one
// barrier, then each wave runs its short chain (<=8 rot6d vs 19) from LDS;
// offsets (~5-9 small loads/thread) stay per-lane global. LDS 78.8KB -> 2
// blocks/CU = 20 waves/CU (2.5x R7 TLP), serial chain 2.4x shorter.
//
// Chains: T0: 0-1-4-7->ee10   T1: 0-2-5-8->ee11   T2: 0-3-6-9-12->ee15
//         T3: 0-3-6-9-13-16-18-20->ee22   T4: 0-3-6-9-14-17-19-21->ee23

struct V3 { float x, y, z; };
struct M3 { float m[3][3]; };   // row r = basis vector b_r (row-stacked)

__device__ __forceinline__ V3 matvec(const M3& A, const V3& v) {
    return { A.m[0][0]*v.x + A.m[0][1]*v.y + A.m[0][2]*v.z,
             A.m[1][0]*v.x + A.m[1][1]*v.y + A.m[1][2]*v.z,
             A.m[2][0]*v.x + A.m[2][1]*v.y + A.m[2][2]*v.z };
}

__device__ __forceinline__ M3 matmul(const M3& A, const M3& B) {
    M3 C;
#pragma unroll
    for (int i = 0; i < 3; i++)
#pragma unroll
        for (int j = 0; j < 3; j++)
            C.m[i][j] = A.m[i][0]*B.m[0][j] + A.m[i][1]*B.m[1][j] + A.m[i][2]*B.m[2][j];
    return C;
}

#define PROW 146   // 144 pose words/frame + 2 pad; gcd(146,32)=2 (free), even->b64

// Gram-Schmidt from 6 LDS floats at rp + 6*J (rp = this thread's frame row).
template<int J>
__device__ __forceinline__ M3 rot6d_lds(const float* __restrict__ rp) {
    const float* p = rp + 6 * J;
    float v0 = p[0], v1 = p[1], v2 = p[2], v3 = p[3], v4 = p[4], v5 = p[5];
    float n1 = v0*v0 + v1*v1 + v2*v2;
    float r1 = 1.0f / sqrtf(n1);
    V3 b1 = { v0*r1, v1*r1, v2*r1 };
    float d = b1.x*v3 + b1.y*v4 + b1.z*v5;
    V3 u = { v3 - d*b1.x, v4 - d*b1.y, v5 - d*b1.z };
    float n2 = u.x*u.x + u.y*u.y + u.z*u.z;
    float r2 = 1.0f / sqrtf(n2);
    V3 b2 = { u.x*r2, u.y*r2, u.z*r2 };
    V3 b3 = { b1.y*b2.z - b1.z*b2.y, b1.z*b2.x - b1.x*b2.z, b1.x*b2.y - b1.y*b2.x };
    M3 R;
    R.m[0][0]=b1.x; R.m[0][1]=b1.y; R.m[0][2]=b1.z;
    R.m[1][0]=b2.x; R.m[1][1]=b2.y; R.m[1][2]=b2.z;
    R.m[2][0]=b3.x; R.m[2][1]=b3.y; R.m[2][2]=b3.z;
    return R;
}

// Offset joint J: 3 floats at obase + 3J (global, per-lane). obase 8B-aligned.
template<int J>
__device__ __forceinline__ V3 load_off_j(const float* __restrict__ obase) {
    const float* p = obase + 3 * J;
    if constexpr ((J & 1) == 0) {
        float2 a = *(const float2*)p;
        float  b = p[2];
        return { a.x, a.y, b };
    } else {
        float  a = p[0];
        float2 b = *(const float2*)(p + 1);
        return { a, b.x, b.y };
    }
}

struct FK { M3 o; V3 p; };

template<int J>
__device__ __forceinline__ FK fk_step(const float* __restrict__ rp,
                                      const float* __restrict__ obase,
                                      const FK& par) {
    V3 off = load_off_j<J>(obase);
    V3 t = matvec(par.o, off);
    FK s;
    s.p = { par.p.x + t.x, par.p.y + t.y, par.p.z + t.z };
    s.o = matmul(par.o, rot6d_lds<J>(rp));
    return s;
}

template<int J>
__device__ __forceinline__ V3 fk_end(const float* __restrict__ obase, const FK& par) {
    V3 off = load_off_j<J>(obase);
    V3 t = matvec(par.o, off);
    return { par.p.x + t.x, par.p.y + t.y, par.p.z + t.z };
}

__global__ __launch_bounds__(640)
void ee_loss_kernel(const float* __restrict__ poseA, const float* __restrict__ poseB,
                    const float* __restrict__ offA,  const float* __restrict__ offB,
                    const float* __restrict__ tA,    const float* __restrict__ tB,
                    float* __restrict__ out, float inv_count) {
    __shared__ float s_pose[2][64 * PROW];   // 74.75 KB: [A|B] x 64 frames
    __shared__ float s_eeB[64][15];          // 3.84 KB (stride 15, coprime 32)
    __shared__ float s_inv[6];
    __shared__ float s_d[15];
    __shared__ float s_part[5];

    const int tid  = threadIdx.x;
    const int wid  = tid >> 6;           // 0..9
    const int lane = tid & 63;
    const int task = wid >> 1;           // 0..4 (wave-uniform)
    const bool isB = wid & 1;
    const long long f0 = (long long)blockIdx.x * 64;

    // ---- t_pose constants (before the staging barrier) ----
    if (tid < 6) {
        const float* tp = (tid < 3) ? tA : tB;
        int ax = (tid < 3) ? tid : tid - 3;
        float mn = tp[ax], mx = mn;
#pragma unroll
        for (int j = 1; j < 24; j++) {
            float v = tp[j*3 + ax];
            mn = fminf(mn, v); mx = fmaxf(mx, v);
        }
        s_inv[tid] = 1.0f / (mx - mn);
    }
    if (tid < 15) {
        const int EE[5] = {10, 11, 15, 22, 23};
        int e = tid / 3, ax = tid - 3*e;
        int j = EE[e];
        float mnA = tA[ax], mxA = mnA, mnB = tB[ax], mxB = mnB;
#pragma unroll
        for (int k = 1; k < 24; k++) {
            float a = tA[k*3 + ax], b = tB[k*3 + ax];
            mnA = fminf(mnA, a); mxA = fmaxf(mxA, a);
            mnB = fminf(mnB, b); mxB = fmaxf(mxB, b);
        }
        s_d[tid] = tB[j*3 + ax]/(mxB - mnB) - tA[j*3 + ax]/(mxA - mnA);
    }

    // ---- cooperative full-pose staging: 2 x 64 frames x 36 float4 ----
    // 2304 float4 per pose across 640 threads (k<4 with tail guard).
    {
        const float* __restrict__ srcA = poseA + f0 * 144;
        const float* __restrict__ srcB = poseB + f0 * 144;
#pragma unroll
        for (int k = 0; k < 4; k++) {
            int idx = tid + 640 * k;
            if (idx < 2304) {
                int f = idx / 36, c = idx - 36 * f;      // 36 float4 per frame
                float4 v = *(const float4*)(srcA + f*144 + 4*c);
                float* d = &s_pose[0][f*PROW + 4*c];
                d[0] = v.x; d[1] = v.y; d[2] = v.z; d[3] = v.w;
            }
        }
#pragma unroll
        for (int k = 0; k < 4; k++) {
            int idx = tid + 640 * k;
            if (idx < 2304) {
                int f = idx / 36, c = idx - 36 * f;
                float4 v = *(const float4*)(srcB + f*144 + 4*c);
                float* d = &s_pose[1][f*PROW + 4*c];
                d[0] = v.x; d[1] = v.y; d[2] = v.z; d[3] = v.w;
            }
        }
    }
    __syncthreads();

    const float* rp = &s_pose[isB ? 1 : 0][lane * PROW];   // this frame's pose row
    const float* obase = (isB ? offB : offA) + (f0 + lane) * 72;

    // ---- one short chain per wave (wave-uniform branch, single FK state) ----
    V3 e;
    {
        FK s; s.o = rot6d_lds<0>(rp); s.p = load_off_j<0>(obase);
        if (task == 0) {
            s = fk_step<1>(rp, obase, s);
            s = fk_step<4>(rp, obase, s);
            s = fk_step<7>(rp, obase, s);
            e = fk_end<10>(obase, s);
        } else if (task == 1) {
            s = fk_step<2>(rp, obase, s);
            s = fk_step<5>(rp, obase, s);
            s = fk_step<8>(rp, obase, s);
            e = fk_end<11>(obase, s);
        } else if (task == 2) {
            s = fk_step<3>(rp, obase, s);
            s = fk_step<6>(rp, obase, s);
            s = fk_step<9>(rp, obase, s);
            s = fk_step<12>(rp, obase, s);
            e = fk_end<15>(obase, s);
        } else if (task == 3) {
            s = fk_step<3>(rp, obase, s);
            s = fk_step<6>(rp, obase, s);
            s = fk_step<9>(rp, obase, s);
            s = fk_step<13>(rp, obase, s);
            s = fk_step<16>(rp, obase, s);
            s = fk_step<18>(rp, obase, s);
            s = fk_step<20>(rp, obase, s);
            e = fk_end<22>(obase, s);
        } else {
            s = fk_step<3>(rp, obase, s);
            s = fk_step<6>(rp, obase, s);
            s = fk_step<9>(rp, obase, s);
            s = fk_step<14>(rp, obase, s);
            s = fk_step<17>(rp, obase, s);
            s = fk_step<19>(rp, obase, s);
            s = fk_step<21>(rp, obase, s);
            e = fk_end<23>(obase, s);
        }
    }

    const int col0 = task * 3;
    if (isB) {
        s_eeB[lane][col0 + 0] = e.x;
        s_eeB[lane][col0 + 1] = e.y;
        s_eeB[lane][col0 + 2] = e.z;
    }
    __syncthreads();

    if (!isB) {
        float tx = e.x*s_inv[0] - s_eeB[lane][col0 + 0]*s_inv[3] + s_d[col0 + 0];
        float ty = e.y*s_inv[1] - s_eeB[lane][col0 + 1]*s_inv[4] + s_d[col0 + 1];
        float tz = e.z*s_inv[2] - s_eeB[lane][col0 + 2]*s_inv[5] + s_d[col0 + 2];
        float local = (tx*tx + ty*ty + tz*tz) * inv_count;
#pragma unroll
        for (int off = 32; off > 0; off >>= 1)
            local += __shfl_down(local, off, 64);
        if (lane == 0) s_part[task] = local;
    }
    __syncthreads();
    if (tid == 0)
        atomicAdd(out, ((s_part[0] + s_part[1]) + (s_part[2] + s_part[3])) + s_part[4]);
}

extern "C" void kernel_launch(void* const* d_in, const int* in_sizes, int n_in,
                              void* d_out, int out_size, void* d_ws, size_t ws_size,
                              hipStream_t stream) {
    const float* poseA = (const float*)d_in[0];
    const float* poseB = (const float*)d_in[1];
    const float* offA  = (const float*)d_in[2];
    const float* offB  = (const float*)d_in[3];
    const float* tA    = (const float*)d_in[4];
    const float* tB    = (const float*)d_in[5];
    float* out = (float*)d_out;

    const int F = in_sizes[0] / 144;          // 65536
    const int blocks = F / 64;                // 1024 blocks, 10 waves each
    const float inv_count = 1.0f / ((float)F * 15.0f);

    hipMemsetAsync(out, 0, sizeof(float), stream);
    ee_loss_kernel<<<blocks, 640, 0, stream>>>(poseA, poseB, offA, offB, tA, tB,
                                               out, inv_count);
}